// Round 6
// baseline (105.642 us; speedup 1.0000x reference)
//
#include <hip/hip_runtime.h>

// out[b,f,t] = sum_{c,dt} exp(-g*x[b,c,t+dt])[x!=0] * w[c*48+dt*16+f]
// im2col GEMM, M=t (98/batch), N=f (16), K=(c,dt). MFMA bf16 16x16x32.
// E stored TRANSPOSED in LDS: ET[t][c] -> A-fragment = one ds_read_b128.
#define BB     64
#define NNCH   10000
#define TT     100
#define TOUT   98
#define FF     16
#define CPB    64                 // channels per block
#define NCHUNK 157                // ceil(10000/64)
#define ETP    72                 // ET row pitch (ushort): 64 data + 8 pad (144 B)
#define ETROWS 116                // t rows 0..113 used (113 = 6*16+15+2)
#define WP     200                // W row pitch (ushort)
#define ACCN   (TOUT * FF)        // 1568

typedef __attribute__((ext_vector_type(8))) short s8v;   // 8 bf16
typedef __attribute__((ext_vector_type(4))) float f4v;   // 4 fp32 acc

__device__ __forceinline__ ushort bf_rne(float v) {
    unsigned b = __float_as_uint(v);
    return (ushort)((b + 0x7FFFu + ((b >> 16) & 1u)) >> 16);
}

__global__ __launch_bounds__(256) void tgcnn_mfma(
    const float* __restrict__ x,      // (B, NN, T) fp32
    const float* __restrict__ w,      // (NN*FS, F) fp32: c*48 + dt*16 + f
    const float* __restrict__ gammat, // fp32 scalar
    float* __restrict__ ws)           // fp32 accum (B, TOUT, F)
{
    __shared__ __align__(16) ushort ET[ETROWS][ETP];  // E^T[t][c], 16704 B
    __shared__ __align__(16) ushort W[FF][WP];        // W[f][dt*64+c], 6400 B

    const int tid = threadIdx.x;
    const int bid = blockIdx.x;
    const int b   = bid / NCHUNK;
    const int cs  = bid - b * NCHUNK;
    const int cbase = cs * CPB;

    const float gt    = gammat[0];
    const float gamma = 10.0f / (1.0f + __expf(-gt));
    const float kk    = -gamma * 1.4426950408889634f;   // exp(-g*x)=exp2(kk*x)

    // zero both LDS regions (covers t-pad rows, pitch pad, tail-chunk channels)
    {
        const uint4 z = make_uint4(0, 0, 0, 0);
        uint4* e4 = (uint4*)&ET[0][0];
        #pragma unroll
        for (int i = tid; i < (ETROWS * ETP * 2) / 16; i += 256) e4[i] = z;
        uint4* w4 = (uint4*)&W[0][0];
        for (int i = tid; i < (FF * WP * 2) / 16; i += 256) w4[i] = z;
    }
    __syncthreads();

    // Stage E transposed: wave handles 64 channels at one t-quad.
    // lane cl = tid&63 loads x[b, cbase+cl, 4q..4q+3]; rows stay L1-resident
    // across q. Writes: word = const + cl/2 -> conflict-free.
    const float4* x4 = (const float4*)x;
    const int cl = tid & 63;
    const int c  = cbase + cl;
    const bool cok = (c < NNCH);
    const size_t xrow = ((size_t)b * NNCH + c) * 25;
    #pragma unroll
    for (int r = 0; r < 7; ++r) {
        const int q = r * 4 + (tid >> 6);
        if (q < 25 && cok) {
            float4 v = x4[xrow + q];
            const int t0 = q * 4;
            ET[t0 + 0][cl] = (v.x != 0.f) ? bf_rne(exp2f(kk * v.x)) : 0;
            ET[t0 + 1][cl] = (v.y != 0.f) ? bf_rne(exp2f(kk * v.y)) : 0;
            ET[t0 + 2][cl] = (v.z != 0.f) ? bf_rne(exp2f(kk * v.z)) : 0;
            ET[t0 + 3][cl] = (v.w != 0.f) ? bf_rne(exp2f(kk * v.w)) : 0;
        }
    }

    // Stage W: w[c*48 + dt*16 + f] -> W[f][dt*64 + cl]
    const float4* wg4 = (const float4*)w;
    if (tid < 192) {   // hmm-free: 768 tiles over 4 rounds of 192 threads
        #pragma unroll
        for (int rr = 0; rr < 4; ++rr) {
            const int i  = rr * 192 + tid;
            const int wc = i / 12, r = i - wc * 12;
            if (cbase + wc < NNCH) {
                float4 wv = wg4[(size_t)(cbase + wc) * 12 + r];
                const int dt = r >> 2, fq = (r & 3) * 4;
                const int kp = dt * CPB + wc;
                W[fq + 0][kp] = bf_rne(wv.x);
                W[fq + 1][kp] = bf_rne(wv.y);
                W[fq + 2][kp] = bf_rne(wv.z);
                W[fq + 3][kp] = bf_rne(wv.w);
            }
        }
    }
    __syncthreads();

    // MFMA: 7 t-tiles (M=112, t>=98 masked); wave owns tiles {wave, wave+4}
    const int wave = tid >> 6, lane = tid & 63;
    const int tcol = lane & 15;        // t within tile (A row) / f (B col, D col)
    const int kb   = lane >> 4;        // k-octet
    const int tile0 = wave, tile1 = wave + 4;

    f4v acc0 = {0.f, 0.f, 0.f, 0.f};
    f4v acc1 = {0.f, 0.f, 0.f, 0.f};

    #pragma unroll
    for (int ks = 0; ks < 6; ++ks) {
        const int dt = ks >> 1;             // k' = ks*32..+32 : dt = ks/2
        const int cb = (ks & 1) * 32 + kb * 8;

        s8v bfrag = *(const s8v*)&W[tcol][ks * 32 + kb * 8];

        const int trow0 = tile0 * 16 + tcol + dt;
        s8v a0 = *(const s8v*)&ET[trow0][cb];
        acc0 = __builtin_amdgcn_mfma_f32_16x16x32_bf16(a0, bfrag, acc0, 0, 0, 0);

        if (tile1 < 7) {
            const int trow1 = tile1 * 16 + tcol + dt;
            s8v a1 = *(const s8v*)&ET[trow1][cb];
            acc1 = __builtin_amdgcn_mfma_f32_16x16x32_bf16(a1, bfrag, acc1, 0, 0, 0);
        }
    }

    // C/D: col = lane&15 (=f), row = (lane>>4)*4 + r (= t within tile)
    float* wsb = ws + (size_t)b * ACCN;
    const int f = lane & 15;
    const int rbase = (lane >> 4) * 4;
    #pragma unroll
    for (int r = 0; r < 4; ++r) {
        const int m = tile0 * 16 + rbase + r;
        if (m < TOUT) atomicAdd(&wsb[m * FF + f], acc0[r]);
    }
    if (tile1 < 7) {
        #pragma unroll
        for (int r = 0; r < 4; ++r) {
            const int m = tile1 * 16 + rbase + r;
            if (m < TOUT) atomicAdd(&wsb[m * FF + f], acc1[r]);
        }
    }
}

__global__ __launch_bounds__(256) void tgcnn_finalize(
    const float* __restrict__ ws, float* __restrict__ out)
{
    int i = blockIdx.x * 256 + threadIdx.x;
    if (i >= BB * FF * TOUT) return;
    int t = i % TOUT;
    int f = (i / TOUT) & (FF - 1);
    int b = i / (FF * TOUT);
    out[i] = ws[(size_t)b * ACCN + t * FF + f];   // (B,T,F) -> (B,F,1,T)
}

extern "C" void kernel_launch(void* const* d_in, const int* in_sizes, int n_in,
                              void* d_out, int out_size, void* d_ws, size_t ws_size,
                              hipStream_t stream) {
    const float* x = (const float*)d_in[0];
    const float* w = (const float*)d_in[1];
    const float* g = (const float*)d_in[2];
    float* ws = (float*)d_ws;

    hipMemsetAsync(d_ws, 0, (size_t)BB * ACCN * sizeof(float), stream);
    tgcnn_mfma<<<BB * NCHUNK, 256, 0, stream>>>(x, w, g, ws);
    tgcnn_finalize<<<(BB * FF * TOUT + 255) / 256, 256, 0, stream>>>(
        ws, (float*)d_out);
}